// Round 8
// baseline (489.458 us; speedup 1.0000x reference)
//
#include <hip/hip_runtime.h>
#include <stdint.h>

// ModeloNeuralVasicek — two-phase mean-recursion.
// Round 24: ONE-WAVE scan, zero barriers. R23 (200us phase2) was barrier-
// latency bound: per body ~330cy issue vs 3040cy measured — __syncthreads
// (lgkmcnt(0) drain + 4-wave skew) serialized each body's ~900cy chain.
// Now a single 64-lane wave does everything:
//  - both W2 matrices pinned in 64 AGPR quads (=256 AGPRs, gfx950 unified)
//  - 64 MFMA/body (16 col-chunks x 4 K); rows repeat (val,dr,dt,zero) per 4,
//    so lane (q,n) EPIs 4 columns; dpp_reduce63 = full 128-col sum
//  - msum -> 6 loop-carried registers (readlane 63); NO LDS exchange
//  - h1 LDS is same-wave write->read (in-order); NO __syncthreads in loop
//  - preamble waves compute ctx + c1 columns -> LDS -> retire
// Phase1: ballot-guarded rare erfinv branch (bit-identical, ~81% waves skip).

#define NSTEPS 2520
#define NB 64
#define NT 256
#define NQ 256
#define NMAT 7
#define NBODY 158
#define MWPAD 2576

typedef uint32_t u32x4 __attribute__((ext_vector_type(4)));
typedef float f32x4 __attribute__((ext_vector_type(4)));

__device__ __forceinline__ uint32_t rotl32(uint32_t v, int n) {
  return (v << n) | (v >> (32 - n));
}

// Threefry-2x32, 20 rounds — matches jax._src.prng.threefry2x32 exactly.
__device__ __forceinline__ void tf2x32(uint32_t k0, uint32_t k1,
                                       uint32_t x0, uint32_t x1,
                                       uint32_t& o0, uint32_t& o1) {
  const uint32_t k2 = k0 ^ k1 ^ 0x1BD11BDAu;
  x0 += k0; x1 += k1;
#define R4(a,b,c,d) \
  x0 += x1; x1 = rotl32(x1,(a)); x1 ^= x0; \
  x0 += x1; x1 = rotl32(x1,(b)); x1 ^= x0; \
  x0 += x1; x1 = rotl32(x1,(c)); x1 ^= x0; \
  x0 += x1; x1 = rotl32(x1,(d)); x1 ^= x0;
  R4(13,15,26,6)  x0 += k1; x1 += k2 + 1u;
  R4(17,29,16,24) x0 += k2; x1 += k0 + 2u;
  R4(13,15,26,6)  x0 += k0; x1 += k1 + 3u;
  R4(17,29,16,24) x0 += k1; x1 += k2 + 4u;
  R4(13,15,26,6)  x0 += k2; x1 += k0 + 5u;
#undef R4
  o0 = x0; o1 = x1;
}

// fast reciprocal: v_rcp + one Newton step (~1e-7 rel)
__device__ __forceinline__ float fast_rcp(float q) {
  float r = __builtin_amdgcn_rcpf(q);
  r = __builtin_fmaf(r, __builtin_fmaf(-q, r, 1.0f), r);
  return r;
}

// Eigen/XLA generic_fast_tanh_float (context aggregator only).
__device__ __forceinline__ float eigen_tanh(float a_x) {
  float x = fminf(fmaxf(a_x, -7.90531110763549805f), 7.90531110763549805f);
  float x2 = x * x;
  float p = __builtin_fmaf(x2, -2.76076847742355e-16f, 2.00018790482477e-13f);
  p = __builtin_fmaf(x2, p, -8.60467152213735e-11f);
  p = __builtin_fmaf(x2, p, 5.12229709037114e-08f);
  p = __builtin_fmaf(x2, p, 1.48572235717979e-05f);
  p = __builtin_fmaf(x2, p, 6.37261928875436e-04f);
  p = __builtin_fmaf(x2, p, 4.89352455891786e-03f);
  p = x * p;
  float q = __builtin_fmaf(x2, 1.19825839466702e-06f, 1.18534705686654e-04f);
  q = __builtin_fmaf(x2, q, 2.26843463243900e-03f);
  q = __builtin_fmaf(x2, q, 4.89352518554385e-03f);
  float rr = p / q;
  return (fabsf(a_x) < 0.0004f) ? a_x : rr;
}

// Eigen/XLA erf polynomial with rcp-division.
__device__ __forceinline__ float eigen_erf_fast(float a_x) {
  float x = fminf(fmaxf(a_x, -4.0f), 4.0f);
  float x2 = x * x;
  float p = __builtin_fmaf(x2, -2.72614225801306e-10f, 2.77068142495902e-08f);
  p = __builtin_fmaf(x2, p, -2.10102402082508e-06f);
  p = __builtin_fmaf(x2, p, -5.69250639462346e-05f);
  p = __builtin_fmaf(x2, p, -7.34990630326855e-04f);
  p = __builtin_fmaf(x2, p, -2.95459980854025e-03f);
  p = __builtin_fmaf(x2, p, -1.60960333262415e-02f);
  p = x * p;
  float q = __builtin_fmaf(x2, -1.45660718464996e-05f, -2.13374055278905e-04f);
  q = __builtin_fmaf(x2, q, -1.68282697438203e-03f);
  q = __builtin_fmaf(x2, q, -7.37332916720468e-03f);
  q = __builtin_fmaf(x2, q, -1.42647390514189e-02f);
  return p * fast_rcp(q);
}

// XLA chlo.erf_inv f32 — phase 1 only. __logf ~1e-7 rel. Rare branch (w>=5,
// ~0.3% lanes) is ballot-guarded: ~81% of waves skip it; bit-identical.
__device__ __forceinline__ float erfinv_xla(float x) {
  float w = -__logf((1.0f - x) * (1.0f + x));
  float wc = w - 2.5f;
  float p = 2.81022636e-08f;
  p = __builtin_fmaf(p, wc, 3.43273939e-07f);
  p = __builtin_fmaf(p, wc, -3.5233877e-06f);
  p = __builtin_fmaf(p, wc, -4.39150654e-06f);
  p = __builtin_fmaf(p, wc, 0.00021858087f);
  p = __builtin_fmaf(p, wc, -0.00125372503f);
  p = __builtin_fmaf(p, wc, -0.00417768164f);
  p = __builtin_fmaf(p, wc, 0.246640727f);
  p = __builtin_fmaf(p, wc, 1.50140941f);
  if (__ballot(w >= 5.0f)) {
    float ws = sqrtf(w) - 3.0f;
    float pr = -0.000200214257f;
    pr = __builtin_fmaf(pr, ws, 0.000100950558f);
    pr = __builtin_fmaf(pr, ws, 0.00134934322f);
    pr = __builtin_fmaf(pr, ws, -0.00367342844f);
    pr = __builtin_fmaf(pr, ws, 0.00573950773f);
    pr = __builtin_fmaf(pr, ws, -0.0076224613f);
    pr = __builtin_fmaf(pr, ws, 0.00943887047f);
    pr = __builtin_fmaf(pr, ws, 1.00167406f);
    pr = __builtin_fmaf(pr, ws, 2.83297682f);
    p = (w >= 5.0f) ? pr : p;
  }
  return p * x;
}

__device__ __forceinline__ float bits_to_normal(uint32_t bits) {
  const float MINVAL = -0.999999940395355224609375f;
  uint32_t fb = (bits >> 9) | 0x3F800000u;
  float f01 = __uint_as_float(fb) - 1.0f;
  float u = f01 * 2.0f + MINVAL;
  u = fmaxf(u, MINVAL);
  return 1.41421356237309515f * erfinv_xla(u);
}

__device__ __forceinline__ uint16_t f32_to_f16bits(float x) {
  _Float16 hv = (_Float16)x;  // RNE
  return __builtin_bit_cast(uint16_t, hv);
}

__device__ __forceinline__ uint32_t pack_f16x2(float lo, float hi) {
  return (uint32_t)f32_to_f16bits(lo) | ((uint32_t)f32_to_f16bits(hi) << 16);
}

// DPP add: v += dpp_move(v) — VALU pipe. 0x111..0x118 row_shr; 0x142/0x143 bcast.
template <int CTRL, int RMASK>
__device__ __forceinline__ float dpp_add(float v) {
  int x = __builtin_amdgcn_update_dpp(0, __float_as_int(v), CTRL, RMASK, 0xf, true);
  return v + __int_as_float(x);
}

// full-wave sum -> lane 63
__device__ __forceinline__ float dpp_reduce63(float p) {
  p = dpp_add<0x111, 0xf>(p);
  p = dpp_add<0x112, 0xf>(p);
  p = dpp_add<0x114, 0xf>(p);
  p = dpp_add<0x118, 0xf>(p);
  p = dpp_add<0x142, 0xa>(p);
  p = dpp_add<0x143, 0xc>(p);
  return p;
}

// DPP move with explicit identity (bound_ctrl=false keeps OLD for no-src lanes)
template <int CTRL>
__device__ __forceinline__ float dpp_mov(float v, float old) {
  int x = __builtin_amdgcn_update_dpp(__float_as_int(old), __float_as_int(v),
                                      CTRL, 0xf, 0xf, false);
  return __int_as_float(x);
}

__device__ __forceinline__ float readlane_f(float v, int l) {
  return __int_as_float(__builtin_amdgcn_readlane(__float_as_int(v), l));
}

#define DTF  0.00396825396825396826f
#define SQDT 0.06299407883487120442f
#define TSTEP (1.0f / 2519.0f)
#define TSC      64.0f
#define TSC_INV  0.015625f
#define TSC_T    1024.0f
#define TSCT_INV 0.0009765625f
#define INV_SQRT2 0.7071067811865475f
#define PHI_C     0.3989422804014327f

// ---------------- Phase 1: mean_dW[b][s] — fully parallel ----------------
__global__ __launch_bounds__(256)
void vasicek_phase1_meandw(float* __restrict__ ws) {
  const int tid = threadIdx.x;
  const int lane = tid & 63;
  const int wv = tid >> 6;
  const int wid = blockIdx.x * 4 + wv;          // 0 .. 64*2520-1
  const int b = wid / NSTEPS;
  const int s = wid - b * NSTEPS;

  uint32_t kA, kB;
  tf2x32(0u, 1u, 0u, (uint32_t)s, kA, kB);      // split(key(1))[s]

  float sum = 0.f;
#pragma unroll
  for (int i = 0; i < 4; ++i) {
    uint32_t cnt = (uint32_t)(b * NQ + lane + i * 64);
    uint32_t q0, q1;
    tf2x32(kA, kB, 0u, cnt, q0, q1);
    float dw = bits_to_normal(q0 ^ q1) * SQDT;
    sum += dw;
  }
  sum += __shfl_xor(sum, 32, 64); sum += __shfl_xor(sum, 16, 64);
  sum += __shfl_xor(sum, 8, 64);  sum += __shfl_xor(sum, 4, 64);
  sum += __shfl_xor(sum, 2, 64);  sum += __shfl_xor(sum, 1, 64);
  if (lane == 0) ws[b * NSTEPS + s] = sum * (1.0f / 256.0f);
}

// ---- B-fragment machinery, k-PERMUTED (pairing unchanged since R17):
// B dword d of K-chunk T (lane q,n) holds W2 rows (16T+4q+d, 64+16T+4q+d)
// at column 16*C + n (C = 0..7 over this MLP's 128 cols), f16x2 packed.
#define BMK(M, T, C, W2P) \
  u32x4 b_##M##_##T##_##C; { \
  const int col_ = 16 * (C) + n; \
  const int r0_ = 16 * (T) + 4 * q; \
  b_##M##_##T##_##C = (u32x4){ \
    pack_f16x2(W2P[(r0_ + 0) * 128 + col_], W2P[(r0_ + 64) * 128 + col_]), \
    pack_f16x2(W2P[(r0_ + 1) * 128 + col_], W2P[(r0_ + 65) * 128 + col_]), \
    pack_f16x2(W2P[(r0_ + 2) * 128 + col_], W2P[(r0_ + 66) * 128 + col_]), \
    pack_f16x2(W2P[(r0_ + 3) * 128 + col_], W2P[(r0_ + 67) * 128 + col_])}; \
  asm volatile("" : "+a"(b_##M##_##T##_##C)); /* pin in AGPR quad */ }

#define MFMA1(ACC, AF, BF) \
  asm("v_mfma_f32_16x16x32_f16 %0, %1, %2, %0" : "+v"(ACC) : "v"(AF), "a"(BF));

// both MLPs, one K-chunk: 16 MFMAs (acc dep distance 16)
#define MROW(T) \
  MFMA1(am0, afm##T, b_m_##T##_0) MFMA1(am1, afm##T, b_m_##T##_1) \
  MFMA1(am2, afm##T, b_m_##T##_2) MFMA1(am3, afm##T, b_m_##T##_3) \
  MFMA1(am4, afm##T, b_m_##T##_4) MFMA1(am5, afm##T, b_m_##T##_5) \
  MFMA1(am6, afm##T, b_m_##T##_6) MFMA1(am7, afm##T, b_m_##T##_7) \
  MFMA1(as0, afs##T, b_s_##T##_0) MFMA1(as1, afs##T, b_s_##T##_1) \
  MFMA1(as2, afs##T, b_s_##T##_2) MFMA1(as3, afs##T, b_s_##T##_3) \
  MFMA1(as4, afs##T, b_s_##T##_4) MFMA1(as5, afs##T, b_s_##T##_5) \
  MFMA1(as6, afs##T, b_s_##T##_6) MFMA1(as7, afs##T, b_s_##T##_7)

// layer-1 one-eval (gelu val + derivative) for element 64E+lane of mlp M
#define STG1(M, E, ANCH, TV) \
  float pre##M##E = __builtin_fmaf((TV), w11v[M][E], \
                      __builtin_fmaf((ANCH), w10v[M][E], c1v[M][E])); \
  float er##M##E = eigen_erf_fast(pre##M##E * INV_SQRT2); \
  float cg##M##E = (er##M##E + 1.0f) * 0.5f; \
  float vv##M##E = pre##M##E * cg##M##E; \
  float ph##M##E = PHI_C * __expf(-0.5f * pre##M##E * pre##M##E); \
  float gp##M##E = __builtin_fmaf(pre##M##E, ph##M##E, cg##M##E);

// full layer-1 stage for a batch: 4 gelu, 6 packed b32 writes
#define STAGE_ALL(SLOT, ANCH, TVAL) { \
  const float tv_ = (TVAL); const float an_ = (ANCH); \
  STG1(0, 0, an_, tv_) STG1(0, 1, an_, tv_) \
  STG1(1, 0, an_, tv_) STG1(1, 1, an_, tv_) \
  h1x[SLOT][0][0][lane] = pack_f16x2(vv00, vv01); \
  h1x[SLOT][0][1][lane] = pack_f16x2(gp00 * w10S[0][0], gp01 * w10S[0][1]); \
  h1x[SLOT][0][2][lane] = pack_f16x2(gp00 * w11Ts[0][0], gp01 * w11Ts[0][1]); \
  h1x[SLOT][1][0][lane] = pack_f16x2(vv10, vv11); \
  h1x[SLOT][1][1][lane] = pack_f16x2(gp10 * w10S[1][0], gp11 * w10S[1][1]); \
  h1x[SLOT][1][2][lane] = pack_f16x2(gp10 * w11Ts[1][0], gp11 * w11Ts[1][1]); \
}

// epilogue for one column: acc elems 0/1/2 = val/dr/dt rows
__device__ __forceinline__ void epi1(f32x4 aq, float b2, float w3,
                                     float& pv, float& pr, float& pt) {
  float yv = aq[0] + b2;
  float ev = eigen_erf_fast(yv * INV_SQRT2);
  float cv = (ev + 1.0f) * 0.5f;
  pv = __builtin_fmaf(yv * cv, w3, pv);
  float phv = PHI_C * __expf(-0.5f * yv * yv);
  float g2p = __builtin_fmaf(yv, phv, cv) * w3;
  pr = __builtin_fmaf(g2p, aq[1], pr);
  pt = __builtin_fmaf(g2p, aq[2], pt);
}

// ---------------- Phase 2: scan, 64 blocks x 256 (loop: wave 0 only) -------
__global__
__attribute__((amdgpu_flat_work_group_size(256, 256)))
__attribute__((amdgpu_waves_per_eu(1, 1)))
void vasicek_phase2_scan(
    const float* __restrict__ X, const float* __restrict__ r_ult,
    const float* __restrict__ mats,
    const float* __restrict__ Wp, const float* __restrict__ bp,
    const float* __restrict__ ln_g, const float* __restrict__ ln_b,
    const float* __restrict__ muW1, const float* __restrict__ mub1,
    const float* __restrict__ muW2, const float* __restrict__ mub2,
    const float* __restrict__ muW3, const float* __restrict__ mub3,
    const float* __restrict__ siW1, const float* __restrict__ sib1,
    const float* __restrict__ siW2, const float* __restrict__ sib2,
    const float* __restrict__ siW3, const float* __restrict__ sib3,
    const float* __restrict__ ws, float* __restrict__ out) {
  // [slot][mlp][region: 0=val,1=dr,2=dt,3=zero][68 dw] (stride 272B==16 mod 128)
  __shared__ __align__(16) uint32_t h1x[2][2][4][68];
  __shared__ __align__(16) float meanw[MWPAD];
  __shared__ float part[256];
  __shared__ float mbuf[64];
  __shared__ float ctx_lds[192];
  __shared__ float c1buf[2][2][64];               // [mlp][half][lane]

  const int t = threadIdx.x;
  const int b = blockIdx.x;
  const int lane = t & 63;
  const int wv = t >> 6;

  for (int i = t; i < MWPAD; i += 256)
    meanw[i] = i < NSTEPS ? ws[b * NSTEPS + i] : 0.f;

  // ---- context aggregator (all 256 threads, one T-row each) ----
  float h[64];
  {
    float x0 = X[(b * NT + t) * 2 + 0];
    float x1 = X[(b * NT + t) * 2 + 1];
    float s = 0.f;
#pragma unroll
    for (int c = 0; c < 64; ++c) {
      float pre = __builtin_fmaf(x1, Wp[64 + c], x0 * Wp[c]) + bp[c];
      h[c] = eigen_tanh(pre);
      s += h[c];
    }
    float m = s * 0.015625f;
    float vs = 0.f;
#pragma unroll
    for (int c = 0; c < 64; ++c) { float d = h[c] - m; vs = __builtin_fmaf(d, d, vs); }
    float den = sqrtf(vs * 0.015625f + 1e-5f);
#pragma unroll
    for (int c = 0; c < 64; ++c)
      h[c] = ((h[c] - m) / den) * ln_g[c] + ln_b[c];
  }
#pragma unroll
  for (int c = 0; c < 64; ++c) {
    float v = h[c];
    v += __shfl_xor(v, 32, 64); v += __shfl_xor(v, 16, 64);
    v += __shfl_xor(v, 8, 64);  v += __shfl_xor(v, 4, 64);
    v += __shfl_xor(v, 2, 64);  v += __shfl_xor(v, 1, 64);
    if (lane == 0) part[wv * 64 + c] = v;
  }
  __syncthreads();
  if (t < 64) {
    float m = ((part[t] + part[64 + t]) + (part[128 + t] + part[192 + t])) * (1.0f / 256.0f);
    mbuf[t] = m;
    ctx_lds[t] = m;
  }
  __syncthreads();
#pragma unroll
  for (int c = 0; c < 64; ++c) {
    float d = h[c] - mbuf[c];
    float v = d * d;
    v += __shfl_xor(v, 32, 64); v += __shfl_xor(v, 16, 64);
    v += __shfl_xor(v, 8, 64);  v += __shfl_xor(v, 4, 64);
    v += __shfl_xor(v, 2, 64);  v += __shfl_xor(v, 1, 64);
    if (lane == 0) part[wv * 64 + c] = v;
  }
  if (t == 255) {
#pragma unroll
    for (int c = 0; c < 64; ++c) ctx_lds[128 + c] = h[c];
  }
  __syncthreads();
  if (t < 64) {
    float vs = (part[t] + part[64 + t]) + (part[128 + t] + part[192 + t]);
    ctx_lds[64 + t] = sqrtf(vs / 255.0f);
  }
  __syncthreads();

  // ---- c1 columns: each wave (mlp=wv>>1, half=wv&1) computes its 64 ----
  {
    const int mlp = wv >> 1;
    const int half = wv & 1;
    const int jH = 64 * half + lane;
    const float* W1 = mlp == 0 ? muW1 : siW1;
    float c1 = (mlp == 0 ? mub1 : sib1)[jH];
    for (int c = 0; c < 192; ++c) {
      const float cx = ctx_lds[c];
      c1 = __builtin_fmaf(cx, W1[(2 + c) * 128 + jH], c1);
    }
    c1buf[mlp][half][lane] = c1;
  }
  // zero region 3 (A-rows 3,7,11,15) for both slots & mlps
  if (t < 68) {
    h1x[0][0][3][t] = 0u; h1x[0][1][3][t] = 0u;
    h1x[1][0][3][t] = 0u; h1x[1][1][3][t] = 0u;
  }
  __syncthreads();   // the LAST barrier
  if (wv != 0) return;

  // =================== wave 0 only from here ===================
  const int q = lane >> 4, n = lane & 15;

  float c1v[2][2], w10v[2][2], w11v[2][2], w10S[2][2], w11Ts[2][2];
#pragma unroll
  for (int m = 0; m < 2; ++m) {
    const float* W1m = m == 0 ? muW1 : siW1;
#pragma unroll
    for (int e = 0; e < 2; ++e) {
      c1v[m][e] = c1buf[m][e][lane];
      w10v[m][e] = W1m[64 * e + lane];
      w11v[m][e] = W1m[128 + 64 * e + lane];
      w10S[m][e] = w10v[m][e] * TSC;
      w11Ts[m][e] = w11v[m][e] * (TSTEP * TSC_T);
    }
  }
  const float b3mu = mub3[0], b3si = sib3[0];

  // per-lane epilogue constants: cols 16q+n and 16q+n+64 of each MLP
  const int ca = 16 * q + n;
  const float b2m0 = mub2[ca],      w3m0 = muW3[ca];
  const float b2m1 = mub2[ca + 64], w3m1 = muW3[ca + 64];
  const float b2s0 = sib2[ca],      w3s0 = siW3[ca];
  const float b2s1 = sib2[ca + 64], w3s1 = siW3[ca + 64];

  // both W2 matrices -> 64 AGPR quads (256 AGPRs; one-time)
  const float* W2m = muW2;
  const float* W2s = siW2;
  BMK(m,0,0,W2m) BMK(m,0,1,W2m) BMK(m,0,2,W2m) BMK(m,0,3,W2m)
  BMK(m,0,4,W2m) BMK(m,0,5,W2m) BMK(m,0,6,W2m) BMK(m,0,7,W2m)
  BMK(m,1,0,W2m) BMK(m,1,1,W2m) BMK(m,1,2,W2m) BMK(m,1,3,W2m)
  BMK(m,1,4,W2m) BMK(m,1,5,W2m) BMK(m,1,6,W2m) BMK(m,1,7,W2m)
  BMK(m,2,0,W2m) BMK(m,2,1,W2m) BMK(m,2,2,W2m) BMK(m,2,3,W2m)
  BMK(m,2,4,W2m) BMK(m,2,5,W2m) BMK(m,2,6,W2m) BMK(m,2,7,W2m)
  BMK(m,3,0,W2m) BMK(m,3,1,W2m) BMK(m,3,2,W2m) BMK(m,3,3,W2m)
  BMK(m,3,4,W2m) BMK(m,3,5,W2m) BMK(m,3,6,W2m) BMK(m,3,7,W2m)
  BMK(s,0,0,W2s) BMK(s,0,1,W2s) BMK(s,0,2,W2s) BMK(s,0,3,W2s)
  BMK(s,0,4,W2s) BMK(s,0,5,W2s) BMK(s,0,6,W2s) BMK(s,0,7,W2s)
  BMK(s,1,0,W2s) BMK(s,1,1,W2s) BMK(s,1,2,W2s) BMK(s,1,3,W2s)
  BMK(s,1,4,W2s) BMK(s,1,5,W2s) BMK(s,1,6,W2s) BMK(s,1,7,W2s)
  BMK(s,2,0,W2s) BMK(s,2,1,W2s) BMK(s,2,2,W2s) BMK(s,2,3,W2s)
  BMK(s,2,4,W2s) BMK(s,2,5,W2s) BMK(s,2,6,W2s) BMK(s,2,7,W2s)
  BMK(s,3,0,W2s) BMK(s,3,1,W2s) BMK(s,3,2,W2s) BMK(s,3,3,W2s)
  BMK(s,3,4,W2s) BMK(s,3,5,W2s) BMK(s,3,6,W2s) BMK(s,3,7,W2s)

  // A-frag base pointers: region (n&3), quad offset q; K-chunk T at +4T quads
  const u32x4* hqm0 = ((const u32x4*)&h1x[0][0][0][0]) + 17 * (n & 3) + q;
  const u32x4* hqm1 = ((const u32x4*)&h1x[1][0][0][0]) + 17 * (n & 3) + q;
  const u32x4* hqs0 = ((const u32x4*)&h1x[0][1][0][0]) + 17 * (n & 3) + q;
  const u32x4* hqs1 = ((const u32x4*)&h1x[1][1][0][0]) + 17 * (n & 3) + q;

  // ---- scan state (wave-uniform) + per-lane area; carried msum registers ----
  const float r0 = r_ult[b];
  float r_s = r0;
  float aNow = r0, aUpd = r0, aMid = r0;   // anchors: batch k, k+1, k+2
  float area_p = 0.f;
  const int sj = lane & 15;
  const float jj = (float)sj - 7.5f;
  float cMV = 0.f, cMR = 0.f, cMT = 0.f, cZV = 0.f, cZR = 0.f, cZT = 0.f;

  // ---- prologue: layer-1 one-eval for batch 0 -> slot 0, anchor r0 ----
  STAGE_ALL(0, r0, TSTEP * 7.5f)

  // ---- main loop: body k: scan batch k, MFMA batch k+1, STAGE3 batch k+2
#pragma unroll 1
  for (int k = -1; k < NBODY; ++k) {
    const int sl = k & 1;        // h1 write slot (batch k+2)
    const int so = sl ^ 1;       // h1 read slot (batch k+1)

    // --- A-frag + meanw LDS reads issued first ---
    const u32x4* hm = so ? hqm1 : hqm0;
    const u32x4* hs = so ? hqs1 : hqs0;
    u32x4 afm0 = hm[0], afm1 = hm[4], afm2 = hm[8], afm3 = hm[12];
    u32x4 afs0 = hs[0], afs1 = hs[4], afs2 = hs[8], afs3 = hs[12];
    const int u0 = k < 0 ? 0 : 16 * k;
    const float mwj = meanw[u0 + sj];

    // --- MFMA batch k+1 (both MLPs; matrix pipe) ---
    f32x4 am0 = {0,0,0,0}, am1 = {0,0,0,0}, am2 = {0,0,0,0}, am3 = {0,0,0,0};
    f32x4 am4 = {0,0,0,0}, am5 = {0,0,0,0}, am6 = {0,0,0,0}, am7 = {0,0,0,0};
    f32x4 as0 = {0,0,0,0}, as1 = {0,0,0,0}, as2 = {0,0,0,0}, as3 = {0,0,0,0};
    f32x4 as4 = {0,0,0,0}, as5 = {0,0,0,0}, as6 = {0,0,0,0}, as7 = {0,0,0,0};
    MROW(0) MROW(1) MROW(2) MROW(3)

    // --- STAGE3 batch k+2 (anchor aMid from previous rotation) ---
    STAGE_ALL(sl, aMid, TSTEP * ((float)(16 * (k + 2)) + 7.5f))

    // --- affine scan for batch k (carried msum registers) ---
    if (k >= 0) {
      float MV = cMV + b3mu;
      float MR = cMR * TSC_INV;
      float MT = cMT * TSCT_INV;
      float ZV = cZV + b3si;
      float ZR = cZR * TSC_INV;
      float ZT = cZT * TSCT_INV;
      float e_ = __expf(-fabsf(ZV));
      float sp = fmaxf(ZV, 0.f) + __logf(1.0f + e_) + 1e-5f;
      float inv = fast_rcp(1.0f + e_);
      float sgm = ZV > 0.f ? inv : 1.0f - inv;
      float hcv = 0.5f * sgm * (1.0f - sgm);
      float dzt = jj * ZT;
      float sigj = __builtin_fmaf(2.0f * hcv, dzt, sgm);
      float spj  = __builtin_fmaf(__builtin_fmaf(hcv, dzt, sgm), dzt, sp);
      float sZR = sigj * ZR;
      float beta = __builtin_fmaf(sZR, mwj, __builtin_fmaf(MR, DTF, 1.0f));
      float am_ = __builtin_fmaf(jj, MT, __builtin_fmaf(-aNow, MR, MV));
      float as_ = __builtin_fmaf(-aNow, sZR, spj);
      float alpha = __builtin_fmaf(am_, DTF, as_ * mwj);
      float B = beta, A = alpha;
      {
        float Bs = dpp_mov<0x111>(B, 1.0f), As = dpp_mov<0x111>(A, 0.0f);
        A = __builtin_fmaf(B, As, A); B = B * Bs;
        Bs = dpp_mov<0x112>(B, 1.0f); As = dpp_mov<0x112>(A, 0.0f);
        A = __builtin_fmaf(B, As, A); B = B * Bs;
        Bs = dpp_mov<0x114>(B, 1.0f); As = dpp_mov<0x114>(A, 0.0f);
        A = __builtin_fmaf(B, As, A); B = B * Bs;
        Bs = dpp_mov<0x118>(B, 1.0f); As = dpp_mov<0x118>(A, 0.0f);
        A = __builtin_fmaf(B, As, A); B = B * Bs;
      }
      float rho = __builtin_fmaf(B, r_s, A);
      float contrib = (16 * k + sj) < NSTEPS ? rho * DTF : 0.f;
      area_p += contrib;
      float rn = readlane_f(rho, 15);
      float aNew = __builtin_fmaf(MV, 40.5f * DTF, rn);
      r_s = rn;
      aNow = aUpd; aUpd = aMid; aMid = aNew;
    }

    // --- MFMA dst -> VALU read hazard fence ---
    asm volatile("s_nop 7\n\ts_nop 7"
                 : "+v"(am0), "+v"(am1), "+v"(am2), "+v"(am3),
                   "+v"(am4), "+v"(am5), "+v"(am6), "+v"(am7),
                   "+v"(as0), "+v"(as1), "+v"(as2), "+v"(as3),
                   "+v"(as4), "+v"(as5), "+v"(as6), "+v"(as7));

    // --- epilogue batch k+1: 4 columns/lane; full-wave reduce -> carried ---
    {
      f32x4 A0 = q == 0 ? am0 : q == 1 ? am1 : q == 2 ? am2 : am3;
      f32x4 A1 = q == 0 ? am4 : q == 1 ? am5 : q == 2 ? am6 : am7;
      f32x4 A2 = q == 0 ? as0 : q == 1 ? as1 : q == 2 ? as2 : as3;
      f32x4 A3 = q == 0 ? as4 : q == 1 ? as5 : q == 2 ? as6 : as7;
      float pvm = 0.f, prm = 0.f, ptm = 0.f;
      float pvs = 0.f, prs = 0.f, pts = 0.f;
      epi1(A0, b2m0, w3m0, pvm, prm, ptm);
      epi1(A1, b2m1, w3m1, pvm, prm, ptm);
      epi1(A2, b2s0, w3s0, pvs, prs, pts);
      epi1(A3, b2s1, w3s1, pvs, prs, pts);
      pvm = dpp_reduce63(pvm); prm = dpp_reduce63(prm); ptm = dpp_reduce63(ptm);
      pvs = dpp_reduce63(pvs); prs = dpp_reduce63(prs); pts = dpp_reduce63(pts);
      cMV = readlane_f(pvm, 63); cMR = readlane_f(prm, 63); cMT = readlane_f(ptm, 63);
      cZV = readlane_f(pvs, 63); cZR = readlane_f(prs, 63); cZT = readlane_f(pts, 63);
    }
  }

  // area: 16-lane rows hold replicated per-step partials
  float area = area_p;
  area += __shfl_xor(area, 1, 64);
  area += __shfl_xor(area, 2, 64);
  area += __shfl_xor(area, 4, 64);
  area += __shfl_xor(area, 8, 64);

  if (t < NMAT) {
    float mx = mats[0];
#pragma unroll
    for (int i = 1; i < NMAT; ++i) mx = fmaxf(mx, mats[i]);
    const float mm = mats[t];
    const float frac = mm / (mx + 1e-12f);
    out[b * NMAT + t] = (area * frac) / (mm + 1e-12f);
  }
}

extern "C" void kernel_launch(void* const* d_in, const int* in_sizes, int n_in,
                              void* d_out, int out_size, void* d_ws, size_t ws_size,
                              hipStream_t stream) {
  (void)in_sizes; (void)n_in; (void)ws_size; (void)out_size;
  const float* X      = (const float*)d_in[0];
  const float* r_ult  = (const float*)d_in[1];
  const float* mats   = (const float*)d_in[2];
  const float* Wp     = (const float*)d_in[3];
  const float* bp     = (const float*)d_in[4];
  const float* ln_g   = (const float*)d_in[5];
  const float* ln_b   = (const float*)d_in[6];
  const float* muW1   = (const float*)d_in[7];
  const float* mub1   = (const float*)d_in[8];
  const float* muW2   = (const float*)d_in[9];
  const float* mub2   = (const float*)d_in[10];
  const float* muW3   = (const float*)d_in[11];
  const float* mub3   = (const float*)d_in[12];
  const float* siW1   = (const float*)d_in[13];
  const float* sib1   = (const float*)d_in[14];
  const float* siW2   = (const float*)d_in[15];
  const float* sib2   = (const float*)d_in[16];
  const float* siW3   = (const float*)d_in[17];
  const float* sib3   = (const float*)d_in[18];
  float* ws = (float*)d_ws;   // 64*2520*4 = 645,120 bytes

  hipLaunchKernelGGL(vasicek_phase1_meandw,
                     dim3(NB * NSTEPS / 4), dim3(256), 0, stream, ws);
  hipLaunchKernelGGL(vasicek_phase2_scan,
                     dim3(NB), dim3(256), 0, stream,
                     X, r_ult, mats, Wp, bp, ln_g, ln_b,
                     muW1, mub1, muW2, mub2, muW3, mub3,
                     siW1, sib1, siW2, sib2, siW3, sib3,
                     ws, (float*)d_out);
}

// Round 9
// 275.614 us; speedup vs baseline: 1.7759x; 1.7759x over previous
//
#include <hip/hip_runtime.h>
#include <stdint.h>

// ModeloNeuralVasicek — two-phase mean-recursion.
// Round 25: batch-64 bodies. R24 (1-wave, 302us) showed single-wave has no
// TLP — revert to R23's validated 4-wave structure (200us). R23 analysis:
// ~3040cy/body is per-body FIXED cost (barrier + exposed latencies), and
// since the R23 restructure per-body work is batch-size independent (one
// MLP eval/batch; MFMA rows = val/dr/dt regions; EPI one col/lane). So:
// batch 16 -> 64 steps/body, bodies 158 -> 40.
//  - scan: all 64 lanes (lane = step-in-batch); affine prefix-scan extends
//    across rows via row_bcast15 (rows1,3) + row_bcast31 (rows2,3), the
//    dpp_reduce63 pattern applied to the affine monoid.
//  - t-Taylor +-31.5 steps: 2nd-order h1 err ~3e-7 << f16 noise.
//  - anchor distance ~160 steps, drift-predicted: |r-a|<~0.05, tangent
//    corrects; residual ~2.5e-6 on mu. Everything else identical to R23.

#define NSTEPS 2520
#define NB 64
#define NT 256
#define NQ 256
#define NMAT 7
#define NBODY 40
#define MWPAD 2560

typedef uint32_t u32x4 __attribute__((ext_vector_type(4)));
typedef float f32x4 __attribute__((ext_vector_type(4)));

__device__ __forceinline__ uint32_t rotl32(uint32_t v, int n) {
  return (v << n) | (v >> (32 - n));
}

// Threefry-2x32, 20 rounds — matches jax._src.prng.threefry2x32 exactly.
__device__ __forceinline__ void tf2x32(uint32_t k0, uint32_t k1,
                                       uint32_t x0, uint32_t x1,
                                       uint32_t& o0, uint32_t& o1) {
  const uint32_t k2 = k0 ^ k1 ^ 0x1BD11BDAu;
  x0 += k0; x1 += k1;
#define R4(a,b,c,d) \
  x0 += x1; x1 = rotl32(x1,(a)); x1 ^= x0; \
  x0 += x1; x1 = rotl32(x1,(b)); x1 ^= x0; \
  x0 += x1; x1 = rotl32(x1,(c)); x1 ^= x0; \
  x0 += x1; x1 = rotl32(x1,(d)); x1 ^= x0;
  R4(13,15,26,6)  x0 += k1; x1 += k2 + 1u;
  R4(17,29,16,24) x0 += k2; x1 += k0 + 2u;
  R4(13,15,26,6)  x0 += k0; x1 += k1 + 3u;
  R4(17,29,16,24) x0 += k1; x1 += k2 + 4u;
  R4(13,15,26,6)  x0 += k2; x1 += k0 + 5u;
#undef R4
  o0 = x0; o1 = x1;
}

// fast reciprocal: v_rcp + one Newton step (~1e-7 rel)
__device__ __forceinline__ float fast_rcp(float q) {
  float r = __builtin_amdgcn_rcpf(q);
  r = __builtin_fmaf(r, __builtin_fmaf(-q, r, 1.0f), r);
  return r;
}

// Eigen/XLA generic_fast_tanh_float (context aggregator only).
__device__ __forceinline__ float eigen_tanh(float a_x) {
  float x = fminf(fmaxf(a_x, -7.90531110763549805f), 7.90531110763549805f);
  float x2 = x * x;
  float p = __builtin_fmaf(x2, -2.76076847742355e-16f, 2.00018790482477e-13f);
  p = __builtin_fmaf(x2, p, -8.60467152213735e-11f);
  p = __builtin_fmaf(x2, p, 5.12229709037114e-08f);
  p = __builtin_fmaf(x2, p, 1.48572235717979e-05f);
  p = __builtin_fmaf(x2, p, 6.37261928875436e-04f);
  p = __builtin_fmaf(x2, p, 4.89352455891786e-03f);
  p = x * p;
  float q = __builtin_fmaf(x2, 1.19825839466702e-06f, 1.18534705686654e-04f);
  q = __builtin_fmaf(x2, q, 2.26843463243900e-03f);
  q = __builtin_fmaf(x2, q, 4.89352518554385e-03f);
  float rr = p / q;
  return (fabsf(a_x) < 0.0004f) ? a_x : rr;
}

// Eigen/XLA erf polynomial with rcp-division.
__device__ __forceinline__ float eigen_erf_fast(float a_x) {
  float x = fminf(fmaxf(a_x, -4.0f), 4.0f);
  float x2 = x * x;
  float p = __builtin_fmaf(x2, -2.72614225801306e-10f, 2.77068142495902e-08f);
  p = __builtin_fmaf(x2, p, -2.10102402082508e-06f);
  p = __builtin_fmaf(x2, p, -5.69250639462346e-05f);
  p = __builtin_fmaf(x2, p, -7.34990630326855e-04f);
  p = __builtin_fmaf(x2, p, -2.95459980854025e-03f);
  p = __builtin_fmaf(x2, p, -1.60960333262415e-02f);
  p = x * p;
  float q = __builtin_fmaf(x2, -1.45660718464996e-05f, -2.13374055278905e-04f);
  q = __builtin_fmaf(x2, q, -1.68282697438203e-03f);
  q = __builtin_fmaf(x2, q, -7.37332916720468e-03f);
  q = __builtin_fmaf(x2, q, -1.42647390514189e-02f);
  return p * fast_rcp(q);
}

// XLA chlo.erf_inv f32 — phase 1 only. __logf ~1e-7 rel. Rare branch (w>=5,
// ~0.3% lanes) ballot-guarded: ~81% of waves skip it; bit-identical.
__device__ __forceinline__ float erfinv_xla(float x) {
  float w = -__logf((1.0f - x) * (1.0f + x));
  float wc = w - 2.5f;
  float p = 2.81022636e-08f;
  p = __builtin_fmaf(p, wc, 3.43273939e-07f);
  p = __builtin_fmaf(p, wc, -3.5233877e-06f);
  p = __builtin_fmaf(p, wc, -4.39150654e-06f);
  p = __builtin_fmaf(p, wc, 0.00021858087f);
  p = __builtin_fmaf(p, wc, -0.00125372503f);
  p = __builtin_fmaf(p, wc, -0.00417768164f);
  p = __builtin_fmaf(p, wc, 0.246640727f);
  p = __builtin_fmaf(p, wc, 1.50140941f);
  if (__ballot(w >= 5.0f)) {
    float ws = sqrtf(w) - 3.0f;
    float pr = -0.000200214257f;
    pr = __builtin_fmaf(pr, ws, 0.000100950558f);
    pr = __builtin_fmaf(pr, ws, 0.00134934322f);
    pr = __builtin_fmaf(pr, ws, -0.00367342844f);
    pr = __builtin_fmaf(pr, ws, 0.00573950773f);
    pr = __builtin_fmaf(pr, ws, -0.0076224613f);
    pr = __builtin_fmaf(pr, ws, 0.00943887047f);
    pr = __builtin_fmaf(pr, ws, 1.00167406f);
    pr = __builtin_fmaf(pr, ws, 2.83297682f);
    p = (w >= 5.0f) ? pr : p;
  }
  return p * x;
}

__device__ __forceinline__ float bits_to_normal(uint32_t bits) {
  const float MINVAL = -0.999999940395355224609375f;
  uint32_t fb = (bits >> 9) | 0x3F800000u;
  float f01 = __uint_as_float(fb) - 1.0f;
  float u = f01 * 2.0f + MINVAL;
  u = fmaxf(u, MINVAL);
  return 1.41421356237309515f * erfinv_xla(u);
}

__device__ __forceinline__ uint16_t f32_to_f16bits(float x) {
  _Float16 hv = (_Float16)x;  // RNE
  return __builtin_bit_cast(uint16_t, hv);
}

__device__ __forceinline__ uint32_t pack_f16x2(float lo, float hi) {
  return (uint32_t)f32_to_f16bits(lo) | ((uint32_t)f32_to_f16bits(hi) << 16);
}

// DPP add: v += dpp_move(v). 0x111..0x118 row_shr; 0x142/0x143 row_bcast.
template <int CTRL, int RMASK>
__device__ __forceinline__ float dpp_add(float v) {
  int x = __builtin_amdgcn_update_dpp(0, __float_as_int(v), CTRL, RMASK, 0xf, true);
  return v + __int_as_float(x);
}

// full-wave sum -> lane 63 (validated chain)
__device__ __forceinline__ float dpp_reduce63(float p) {
  p = dpp_add<0x111, 0xf>(p);
  p = dpp_add<0x112, 0xf>(p);
  p = dpp_add<0x114, 0xf>(p);
  p = dpp_add<0x118, 0xf>(p);
  p = dpp_add<0x142, 0xa>(p);
  p = dpp_add<0x143, 0xc>(p);
  return p;
}

// DPP move with explicit identity; RMASK gates which rows receive (others
// keep OLD). bound_ctrl=false keeps OLD for no-src lanes.
template <int CTRL, int RMASK>
__device__ __forceinline__ float dpp_mov(float v, float old) {
  int x = __builtin_amdgcn_update_dpp(__float_as_int(old), __float_as_int(v),
                                      CTRL, RMASK, 0xf, false);
  return __int_as_float(x);
}

__device__ __forceinline__ float readlane_f(float v, int l) {
  return __int_as_float(__builtin_amdgcn_readlane(__float_as_int(v), l));
}

#define DTF  0.00396825396825396826f
#define SQDT 0.06299407883487120442f
#define TSTEP (1.0f / 2519.0f)
#define TSC      64.0f
#define TSC_INV  0.015625f
#define TSC_T    1024.0f
#define TSCT_INV 0.0009765625f
#define INV_SQRT2 0.7071067811865475f
#define PHI_C     0.3989422804014327f

// ---------------- Phase 1: mean_dW[b][s] — fully parallel ----------------
__global__ __launch_bounds__(256)
void vasicek_phase1_meandw(float* __restrict__ ws) {
  const int tid = threadIdx.x;
  const int lane = tid & 63;
  const int wv = tid >> 6;
  const int wid = blockIdx.x * 4 + wv;          // 0 .. 64*2520-1
  const int b = wid / NSTEPS;
  const int s = wid - b * NSTEPS;

  uint32_t kA, kB;
  tf2x32(0u, 1u, 0u, (uint32_t)s, kA, kB);      // split(key(1))[s]

  float sum = 0.f;
#pragma unroll
  for (int i = 0; i < 4; ++i) {
    uint32_t cnt = (uint32_t)(b * NQ + lane + i * 64);
    uint32_t q0, q1;
    tf2x32(kA, kB, 0u, cnt, q0, q1);
    float dw = bits_to_normal(q0 ^ q1) * SQDT;
    sum += dw;
  }
  sum += __shfl_xor(sum, 32, 64); sum += __shfl_xor(sum, 16, 64);
  sum += __shfl_xor(sum, 8, 64);  sum += __shfl_xor(sum, 4, 64);
  sum += __shfl_xor(sum, 2, 64);  sum += __shfl_xor(sum, 1, 64);
  if (lane == 0) ws[b * NSTEPS + s] = sum * (1.0f / 256.0f);
}

// ---- B-fragment machinery, k-PERMUTED (unchanged from R20/R23):
// B dword d of K-chunk T (lane q,n) holds W2 rows (16T+4q+d, 64+16T+4q+d)
// at column 16*(4*half+C) + n, f16x2 packed.
#define BDECL(T, C) u32x4 b_##T##_##C;
#define BINIT(T, C) { \
  const int col_ = 16 * (4 * half + (C)) + n; \
  const int r0_ = 16 * (T) + 4 * q; \
  b_##T##_##C = (u32x4){ \
    pack_f16x2(W2src[(r0_ + 0) * 128 + col_], W2src[(r0_ + 64) * 128 + col_]), \
    pack_f16x2(W2src[(r0_ + 1) * 128 + col_], W2src[(r0_ + 65) * 128 + col_]), \
    pack_f16x2(W2src[(r0_ + 2) * 128 + col_], W2src[(r0_ + 66) * 128 + col_]), \
    pack_f16x2(W2src[(r0_ + 3) * 128 + col_], W2src[(r0_ + 67) * 128 + col_])}; \
  asm volatile("" : "+a"(b_##T##_##C)); /* pin in AGPR quad */ \
}
#define MFMA1(ACC, AF, BF) \
  asm("v_mfma_f32_16x16x32_f16 %0, %1, %2, %0" : "+v"(ACC) : "v"(AF), "a"(BF));

// one-eval layer-1 for a batch: anchor A_, mid-time TV; writes regions
// 0=val, 1=d/dr*64, 2=d/dt_j*1024 (region 3 pre-zeroed).
#define STAGE3M(TV, SLOT, A_) { \
  float pre_ = __builtin_fmaf((TV), w11, __builtin_fmaf((A_), w10, c1)); \
  float e_ = eigen_erf_fast(pre_ * INV_SQRT2); \
  float cg_ = (e_ + 1.0f) * 0.5f; \
  float v_ = pre_ * cg_; \
  float ph_ = PHI_C * __expf(-0.5f * pre_ * pre_); \
  float gp_ = __builtin_fmaf(pre_, ph_, cg_); \
  ((uint16_t*)&h1x[SLOT][mlp][0][0])[2 * lane + half] = f32_to_f16bits(v_); \
  ((uint16_t*)&h1x[SLOT][mlp][1][0])[2 * lane + half] = f32_to_f16bits(gp_ * w10S); \
  ((uint16_t*)&h1x[SLOT][mlp][2][0])[2 * lane + half] = f32_to_f16bits(gp_ * w11T); \
}

// ---------------- Phase 2: scan, 64 blocks x 256 ---------------------------
__global__
__attribute__((amdgpu_flat_work_group_size(256, 256)))
__attribute__((amdgpu_waves_per_eu(1, 1)))
void vasicek_phase2_scan(
    const float* __restrict__ X, const float* __restrict__ r_ult,
    const float* __restrict__ mats,
    const float* __restrict__ Wp, const float* __restrict__ bp,
    const float* __restrict__ ln_g, const float* __restrict__ ln_b,
    const float* __restrict__ muW1, const float* __restrict__ mub1,
    const float* __restrict__ muW2, const float* __restrict__ mub2,
    const float* __restrict__ muW3, const float* __restrict__ mub3,
    const float* __restrict__ siW1, const float* __restrict__ sib1,
    const float* __restrict__ siW2, const float* __restrict__ sib2,
    const float* __restrict__ siW3, const float* __restrict__ sib3,
    const float* __restrict__ ws, float* __restrict__ out) {
  // [slot][mlp][region: 0=val,1=dr,2=dt,3=zero][68 dw] (stride 272B==16 mod 128)
  __shared__ __align__(16) uint32_t h1x[2][2][4][68];
  __shared__ __align__(16) float meanw[MWPAD];
  __shared__ float part[256];
  __shared__ float mbuf[64];
  __shared__ float ctx_lds[192];
  __shared__ __align__(16) float msum[2][4][4];   // [slot][wave][PV,PR,PT,pad]

  const int t = threadIdx.x;
  const int b = blockIdx.x;
  const int lane = t & 63;
  const int wv = t >> 6;

  for (int i = t; i < MWPAD; i += 256)
    meanw[i] = i < NSTEPS ? ws[b * NSTEPS + i] : 0.f;

  // ---- context aggregator (all 256 threads, one T-row each) ----
  float h[64];
  {
    float x0 = X[(b * NT + t) * 2 + 0];
    float x1 = X[(b * NT + t) * 2 + 1];
    float s = 0.f;
#pragma unroll
    for (int c = 0; c < 64; ++c) {
      float pre = __builtin_fmaf(x1, Wp[64 + c], x0 * Wp[c]) + bp[c];
      h[c] = eigen_tanh(pre);
      s += h[c];
    }
    float m = s * 0.015625f;
    float vs = 0.f;
#pragma unroll
    for (int c = 0; c < 64; ++c) { float d = h[c] - m; vs = __builtin_fmaf(d, d, vs); }
    float den = sqrtf(vs * 0.015625f + 1e-5f);
#pragma unroll
    for (int c = 0; c < 64; ++c)
      h[c] = ((h[c] - m) / den) * ln_g[c] + ln_b[c];
  }
#pragma unroll
  for (int c = 0; c < 64; ++c) {
    float v = h[c];
    v += __shfl_xor(v, 32, 64); v += __shfl_xor(v, 16, 64);
    v += __shfl_xor(v, 8, 64);  v += __shfl_xor(v, 4, 64);
    v += __shfl_xor(v, 2, 64);  v += __shfl_xor(v, 1, 64);
    if (lane == 0) part[wv * 64 + c] = v;
  }
  __syncthreads();
  if (t < 64) {
    float m = ((part[t] + part[64 + t]) + (part[128 + t] + part[192 + t])) * (1.0f / 256.0f);
    mbuf[t] = m;
    ctx_lds[t] = m;
  }
  __syncthreads();
#pragma unroll
  for (int c = 0; c < 64; ++c) {
    float d = h[c] - mbuf[c];
    float v = d * d;
    v += __shfl_xor(v, 32, 64); v += __shfl_xor(v, 16, 64);
    v += __shfl_xor(v, 8, 64);  v += __shfl_xor(v, 4, 64);
    v += __shfl_xor(v, 2, 64);  v += __shfl_xor(v, 1, 64);
    if (lane == 0) part[wv * 64 + c] = v;
  }
  if (t == 255) {
#pragma unroll
    for (int c = 0; c < 64; ++c) ctx_lds[128 + c] = h[c];
  }
  __syncthreads();
  if (t < 64) {
    float vs = (part[t] + part[64 + t]) + (part[128 + t] + part[192 + t]);
    ctx_lds[64 + t] = sqrtf(vs / 255.0f);
  }
  __syncthreads();

  // ---- per-wave roles: mlp = wv>>1 (0=mu,1=si), half = wv&1 ----
  const int mlp = wv >> 1;
  const int half = wv & 1;
  const int jH = 64 * half + lane;            // layer-1 element ownership
  const float* W1 = mlp == 0 ? muW1 : siW1;
  const float* W2src = mlp == 0 ? muW2 : siW2;
  float c1 = (mlp == 0 ? mub1 : sib1)[jH];
  for (int c = 0; c < 192; ++c) {
    const float cx = ctx_lds[c];
    c1 = __builtin_fmaf(cx, W1[(2 + c) * 128 + jH], c1);
  }
  const float w10 = W1[jH], w11 = W1[128 + jH];
  const float w10S = w10 * TSC;
  const float w11T = w11 * (TSTEP * TSC_T);
  const float b3mu = mub3[0], b3si = sib3[0];

  const int q = lane >> 4, n = lane & 15;

  // per-lane epilogue constants: this lane's single column (chunk C = q)
  const float* b2p = mlp == 0 ? mub2 : sib2;
  const float* w3p = mlp == 0 ? muW3 : siW3;
  const int colE = 64 * half + 16 * q + n;
  const float b2E = b2p[colE], w3E = w3p[colE];

  // this wave's 4 col-tiles of its W2 -> 16 AGPR quads (one-time; pinned)
  BDECL(0,0) BDECL(0,1) BDECL(0,2) BDECL(0,3)
  BDECL(1,0) BDECL(1,1) BDECL(1,2) BDECL(1,3)
  BDECL(2,0) BDECL(2,1) BDECL(2,2) BDECL(2,3)
  BDECL(3,0) BDECL(3,1) BDECL(3,2) BDECL(3,3)
  BINIT(0,0) BINIT(0,1) BINIT(0,2) BINIT(0,3)
  BINIT(1,0) BINIT(1,1) BINIT(1,2) BINIT(1,3)
  BINIT(2,0) BINIT(2,1) BINIT(2,2) BINIT(2,3)
  BINIT(3,0) BINIT(3,1) BINIT(3,2) BINIT(3,3)

  // zero region 3 (A-rows 3,7,11,15) for both slots of this wave's MLP
  h1x[0][mlp][3][lane] = 0u; h1x[1][mlp][3][lane] = 0u;
  if (lane < 4) { h1x[0][mlp][3][64 + lane] = 0u; h1x[1][mlp][3][64 + lane] = 0u; }

  // A-frag base pointers: region (n&3) of this wave's MLP, quad offset q.
  const u32x4* hq0 = ((const u32x4*)&h1x[0][mlp][0][0]) + 17 * (n & 3) + q;
  const u32x4* hq1 = ((const u32x4*)&h1x[1][mlp][0][0]) + 17 * (n & 3) + q;

  // ---- scan state (uniform) + per-lane area ----
  const float r0 = r_ult[b];
  float r_s = r0;
  float aNow = r0, aUpd = r0, aMid = r0;   // anchors: batch k, k+1, k+2
  float area_p = 0.f;
  const int sj = lane;                     // step-in-batch (64-wide)
  const float jj = (float)sj - 31.5f;

  // ---- prologue: layer-1 one-eval for batch 0 -> slot 0, anchor r0 ----
  STAGE3M(TSTEP * 31.5f, 0, r0)
  __syncthreads();

  // ---- main loop: body k: scan batch k, MFMA batch k+1, STAGE3 batch k+2
#pragma unroll 1
  for (int k = -1; k < NBODY; ++k) {
    const int sl = k & 1;        // msum slot (batch k); h1 write slot (batch k+2)
    const int so = sl ^ 1;       // h1 read slot (batch k+1); msum write slot

    // --- LDS reads issued early ---
    f32x4 m0 = *(const f32x4*)&msum[sl][0][0];
    f32x4 m1 = *(const f32x4*)&msum[sl][1][0];
    f32x4 m2 = *(const f32x4*)&msum[sl][2][0];
    f32x4 m3 = *(const f32x4*)&msum[sl][3][0];
    const int u0 = k < 0 ? 0 : 64 * k;
    const float mwj = meanw[u0 + sj];
    const u32x4* hq = so ? hq1 : hq0;
    u32x4 af0 = hq[0], af1 = hq[4], af2 = hq[8], af3 = hq[12];

    // --- MFMA batch k+1 (matrix pipe) ---
    f32x4 ac0 = {0,0,0,0}, ac1 = {0,0,0,0}, ac2 = {0,0,0,0}, ac3 = {0,0,0,0};
    MFMA1(ac0, af0, b_0_0) MFMA1(ac1, af0, b_0_1) MFMA1(ac2, af0, b_0_2) MFMA1(ac3, af0, b_0_3)
    MFMA1(ac0, af1, b_1_0) MFMA1(ac1, af1, b_1_1) MFMA1(ac2, af1, b_1_2) MFMA1(ac3, af1, b_1_3)
    MFMA1(ac0, af2, b_2_0) MFMA1(ac1, af2, b_2_1) MFMA1(ac2, af2, b_2_2) MFMA1(ac3, af2, b_2_3)
    MFMA1(ac0, af3, b_3_0) MFMA1(ac1, af3, b_3_1) MFMA1(ac2, af3, b_3_2) MFMA1(ac3, af3, b_3_3)

    // --- STAGE3 batch k+2 (anchor aMid from previous rotation) ---
    STAGE3M(TSTEP * ((float)(64 * (k + 2)) + 31.5f), sl, aMid)

    // --- affine scan for batch k (lane sj = step 64k+sj) ---
    {
      float MV = (m0[0] + m1[0]) + b3mu;
      float MR = (m0[1] + m1[1]) * TSC_INV;
      float MT = (m0[2] + m1[2]) * TSCT_INV;
      float ZV = (m2[0] + m3[0]) + b3si;
      float ZR = (m2[1] + m3[1]) * TSC_INV;
      float ZT = (m2[2] + m3[2]) * TSCT_INV;
      // softplus at z_mid + 2nd-order in the (r-independent) time offset
      float e_ = __expf(-fabsf(ZV));
      float sp = fmaxf(ZV, 0.f) + __logf(1.0f + e_) + 1e-5f;
      float inv = fast_rcp(1.0f + e_);
      float sgm = ZV > 0.f ? inv : 1.0f - inv;
      float hcv = 0.5f * sgm * (1.0f - sgm);
      float dzt = jj * ZT;
      float sigj = __builtin_fmaf(2.0f * hcv, dzt, sgm);    // sigma(z_mid+dzt)
      float spj  = __builtin_fmaf(__builtin_fmaf(hcv, dzt, sgm), dzt, sp);
      float sZR = sigj * ZR;
      // beta, alpha
      float beta = __builtin_fmaf(sZR, mwj, __builtin_fmaf(MR, DTF, 1.0f));
      float am_ = __builtin_fmaf(jj, MT, __builtin_fmaf(-aNow, MR, MV));
      float as_ = __builtin_fmaf(-aNow, sZR, spj);
      float alpha = __builtin_fmaf(am_, DTF, as_ * mwj);
      // inclusive affine prefix scan over 64 lanes:
      // 4 in-row rounds, then row_bcast15 (rows1,3), row_bcast31 (rows2,3)
      float B = beta, A = alpha;
      {
        float Bs = dpp_mov<0x111, 0xf>(B, 1.0f), As = dpp_mov<0x111, 0xf>(A, 0.0f);
        A = __builtin_fmaf(B, As, A); B = B * Bs;
        Bs = dpp_mov<0x112, 0xf>(B, 1.0f); As = dpp_mov<0x112, 0xf>(A, 0.0f);
        A = __builtin_fmaf(B, As, A); B = B * Bs;
        Bs = dpp_mov<0x114, 0xf>(B, 1.0f); As = dpp_mov<0x114, 0xf>(A, 0.0f);
        A = __builtin_fmaf(B, As, A); B = B * Bs;
        Bs = dpp_mov<0x118, 0xf>(B, 1.0f); As = dpp_mov<0x118, 0xf>(A, 0.0f);
        A = __builtin_fmaf(B, As, A); B = B * Bs;
        Bs = dpp_mov<0x142, 0xa>(B, 1.0f); As = dpp_mov<0x142, 0xa>(A, 0.0f);
        A = __builtin_fmaf(B, As, A); B = B * Bs;
        Bs = dpp_mov<0x143, 0xc>(B, 1.0f); As = dpp_mov<0x143, 0xc>(A, 0.0f);
        A = __builtin_fmaf(B, As, A); B = B * Bs;
      }
      float rho = __builtin_fmaf(B, r_s, A);
      if (k >= 0) {
        float contrib = (64 * k + sj) < NSTEPS ? rho * DTF : 0.f;
        area_p += contrib;
        float rn = readlane_f(rho, 63);
        // drift-only prediction for batch k+3 (mid-step distance ~160.5)
        float aNew = __builtin_fmaf(MV, 160.5f * DTF, rn);
        r_s = rn;
        aNow = aUpd; aUpd = aMid; aMid = aNew;
      }
    }

    // --- MFMA dst -> VALU read hazard fence ---
    asm volatile("s_nop 7\n\ts_nop 7"
                 : "+v"(ac0), "+v"(ac1), "+v"(ac2), "+v"(ac3));

    // --- epilogue batch k+1: lane (q,n) handles its single column (C=q) ---
    {
      const f32x4 aq = q == 0 ? ac0 : q == 1 ? ac1 : q == 2 ? ac2 : ac3;
      float yv = aq[0] + b2E;
      float ytr = aq[1];                 // d/dr row (scaled TSC)
      float ytt = aq[2];                 // d/dt row (scaled TSC_T)
      float ev = eigen_erf_fast(yv * INV_SQRT2);
      float cv = (ev + 1.0f) * 0.5f;
      float pv = yv * cv * w3E;
      float phv = PHI_C * __expf(-0.5f * yv * yv);
      float g2p = __builtin_fmaf(yv, phv, cv) * w3E;
      float pr = g2p * ytr;
      float pt = g2p * ytt;
      pv = dpp_reduce63(pv);
      pr = dpp_reduce63(pr);
      pt = dpp_reduce63(pt);
      if (lane == 63) {
        *(f32x4*)&msum[so][wv][0] = (f32x4){pv, pr, pt, 0.f};
      }
    }
    __syncthreads();  // publish msum[so] (batch k+1) + h1x[sl] (batch k+2)
  }

  // area: all 64 lanes hold distinct per-step partials
  float area = area_p;
  area += __shfl_xor(area, 1, 64);
  area += __shfl_xor(area, 2, 64);
  area += __shfl_xor(area, 4, 64);
  area += __shfl_xor(area, 8, 64);
  area += __shfl_xor(area, 16, 64);
  area += __shfl_xor(area, 32, 64);

  if (t < NMAT) {
    float mx = mats[0];
#pragma unroll
    for (int i = 1; i < NMAT; ++i) mx = fmaxf(mx, mats[i]);
    const float mm = mats[t];
    const float frac = mm / (mx + 1e-12f);
    out[b * NMAT + t] = (area * frac) / (mm + 1e-12f);
  }
}

extern "C" void kernel_launch(void* const* d_in, const int* in_sizes, int n_in,
                              void* d_out, int out_size, void* d_ws, size_t ws_size,
                              hipStream_t stream) {
  (void)in_sizes; (void)n_in; (void)ws_size; (void)out_size;
  const float* X      = (const float*)d_in[0];
  const float* r_ult  = (const float*)d_in[1];
  const float* mats   = (const float*)d_in[2];
  const float* Wp     = (const float*)d_in[3];
  const float* bp     = (const float*)d_in[4];
  const float* ln_g   = (const float*)d_in[5];
  const float* ln_b   = (const float*)d_in[6];
  const float* muW1   = (const float*)d_in[7];
  const float* mub1   = (const float*)d_in[8];
  const float* muW2   = (const float*)d_in[9];
  const float* mub2   = (const float*)d_in[10];
  const float* muW3   = (const float*)d_in[11];
  const float* mub3   = (const float*)d_in[12];
  const float* siW1   = (const float*)d_in[13];
  const float* sib1   = (const float*)d_in[14];
  const float* siW2   = (const float*)d_in[15];
  const float* sib2   = (const float*)d_in[16];
  const float* siW3   = (const float*)d_in[17];
  const float* sib3   = (const float*)d_in[18];
  float* ws = (float*)d_ws;   // 64*2520*4 = 645,120 bytes

  hipLaunchKernelGGL(vasicek_phase1_meandw,
                     dim3(NB * NSTEPS / 4), dim3(256), 0, stream, ws);
  hipLaunchKernelGGL(vasicek_phase2_scan,
                     dim3(NB), dim3(256), 0, stream,
                     X, r_ult, mats, Wp, bp, ln_g, ln_b,
                     muW1, mub1, muW2, mub2, muW3, mub3,
                     siW1, sib1, siW2, sib2, siW3, sib3,
                     ws, (float*)d_out);
}

// Round 10
// 270.300 us; speedup vs baseline: 1.8108x; 1.0197x over previous
//
#include <hip/hip_runtime.h>
#include <stdint.h>

// ModeloNeuralVasicek — two-phase mean-recursion.
// Round 26: phase1 instruction diet. R25 (275us total) moved the bottleneck:
// top-5 dispatches are ALL phase1 (~128.5us, VALUBusy saturated). Phase1 is
// pure VALU-throughput bound on 41.3M threefry+erfinv evals. Changes
// (phase2 byte-identical to R25, which passed at absmax 0.0078125):
//  - rotl via explicit v_alignbit_b32 builtin (1 op guaranteed)
//  - 1-u^2 via fma(u,-u,1); wc = fma(log2, -ln2, -2.5) folds neg+scale+bias
//  - per-normal constant chain folded to one fma with C = sqrt2*sqrt(dt)
//  - threefry x1-init pre-keyed (x1 = cnt+kB); rare erfinv branch tested on
//    log2 directly (lg <= -5/ln2), ballot-guarded (~81% waves skip)
// Expected ~90 VALU ops/normal (71 threefry + 19 normal) vs ~120-135 before.

#define NSTEPS 2520
#define NB 64
#define NT 256
#define NQ 256
#define NMAT 7
#define NBODY 40
#define MWPAD 2560

typedef uint32_t u32x4 __attribute__((ext_vector_type(4)));
typedef float f32x4 __attribute__((ext_vector_type(4)));

// 1-op rotate: alignbit(v,v,32-n) = (v<<n)|(v>>(32-n))
__device__ __forceinline__ uint32_t rotl32(uint32_t v, int n) {
  return __builtin_amdgcn_alignbit(v, v, (uint32_t)(32 - n));
}

// Threefry-2x32, 20 rounds — matches jax._src.prng.threefry2x32 exactly.
__device__ __forceinline__ void tf2x32(uint32_t k0, uint32_t k1,
                                       uint32_t x0, uint32_t x1,
                                       uint32_t& o0, uint32_t& o1) {
  const uint32_t k2 = k0 ^ k1 ^ 0x1BD11BDAu;
  x0 += k0; x1 += k1;
#define R4(a,b,c,d) \
  x0 += x1; x1 = rotl32(x1,(a)); x1 ^= x0; \
  x0 += x1; x1 = rotl32(x1,(b)); x1 ^= x0; \
  x0 += x1; x1 = rotl32(x1,(c)); x1 ^= x0; \
  x0 += x1; x1 = rotl32(x1,(d)); x1 ^= x0;
  R4(13,15,26,6)  x0 += k1; x1 += k2 + 1u;
  R4(17,29,16,24) x0 += k2; x1 += k0 + 2u;
  R4(13,15,26,6)  x0 += k0; x1 += k1 + 3u;
  R4(17,29,16,24) x0 += k1; x1 += k2 + 4u;
  R4(13,15,26,6)  x0 += k2; x1 += k0 + 5u;
  o0 = x0; o1 = x1;
}

// fast reciprocal: v_rcp + one Newton step (~1e-7 rel)
__device__ __forceinline__ float fast_rcp(float q) {
  float r = __builtin_amdgcn_rcpf(q);
  r = __builtin_fmaf(r, __builtin_fmaf(-q, r, 1.0f), r);
  return r;
}

// Eigen/XLA generic_fast_tanh_float (context aggregator only).
__device__ __forceinline__ float eigen_tanh(float a_x) {
  float x = fminf(fmaxf(a_x, -7.90531110763549805f), 7.90531110763549805f);
  float x2 = x * x;
  float p = __builtin_fmaf(x2, -2.76076847742355e-16f, 2.00018790482477e-13f);
  p = __builtin_fmaf(x2, p, -8.60467152213735e-11f);
  p = __builtin_fmaf(x2, p, 5.12229709037114e-08f);
  p = __builtin_fmaf(x2, p, 1.48572235717979e-05f);
  p = __builtin_fmaf(x2, p, 6.37261928875436e-04f);
  p = __builtin_fmaf(x2, p, 4.89352455891786e-03f);
  p = x * p;
  float q = __builtin_fmaf(x2, 1.19825839466702e-06f, 1.18534705686654e-04f);
  q = __builtin_fmaf(x2, q, 2.26843463243900e-03f);
  q = __builtin_fmaf(x2, q, 4.89352518554385e-03f);
  float rr = p / q;
  return (fabsf(a_x) < 0.0004f) ? a_x : rr;
}

// Eigen/XLA erf polynomial with rcp-division.
__device__ __forceinline__ float eigen_erf_fast(float a_x) {
  float x = fminf(fmaxf(a_x, -4.0f), 4.0f);
  float x2 = x * x;
  float p = __builtin_fmaf(x2, -2.72614225801306e-10f, 2.77068142495902e-08f);
  p = __builtin_fmaf(x2, p, -2.10102402082508e-06f);
  p = __builtin_fmaf(x2, p, -5.69250639462346e-05f);
  p = __builtin_fmaf(x2, p, -7.34990630326855e-04f);
  p = __builtin_fmaf(x2, p, -2.95459980854025e-03f);
  p = __builtin_fmaf(x2, p, -1.60960333262415e-02f);
  p = x * p;
  float q = __builtin_fmaf(x2, -1.45660718464996e-05f, -2.13374055278905e-04f);
  q = __builtin_fmaf(x2, q, -1.68282697438203e-03f);
  q = __builtin_fmaf(x2, q, -7.37332916720468e-03f);
  q = __builtin_fmaf(x2, q, -1.42647390514189e-02f);
  return p * fast_rcp(q);
}

__device__ __forceinline__ uint16_t f32_to_f16bits(float x) {
  _Float16 hv = (_Float16)x;  // RNE
  return __builtin_bit_cast(uint16_t, hv);
}

__device__ __forceinline__ uint32_t pack_f16x2(float lo, float hi) {
  return (uint32_t)f32_to_f16bits(lo) | ((uint32_t)f32_to_f16bits(hi) << 16);
}

// DPP add: v += dpp_move(v). 0x111..0x118 row_shr; 0x142/0x143 row_bcast.
template <int CTRL, int RMASK>
__device__ __forceinline__ float dpp_add(float v) {
  int x = __builtin_amdgcn_update_dpp(0, __float_as_int(v), CTRL, RMASK, 0xf, true);
  return v + __int_as_float(x);
}

// full-wave sum -> lane 63 (validated chain)
__device__ __forceinline__ float dpp_reduce63(float p) {
  p = dpp_add<0x111, 0xf>(p);
  p = dpp_add<0x112, 0xf>(p);
  p = dpp_add<0x114, 0xf>(p);
  p = dpp_add<0x118, 0xf>(p);
  p = dpp_add<0x142, 0xa>(p);
  p = dpp_add<0x143, 0xc>(p);
  return p;
}

// DPP move with explicit identity; RMASK gates which rows receive (others
// keep OLD). bound_ctrl=false keeps OLD for no-src lanes.
template <int CTRL, int RMASK>
__device__ __forceinline__ float dpp_mov(float v, float old) {
  int x = __builtin_amdgcn_update_dpp(__float_as_int(old), __float_as_int(v),
                                      CTRL, RMASK, 0xf, false);
  return __int_as_float(x);
}

__device__ __forceinline__ float readlane_f(float v, int l) {
  return __int_as_float(__builtin_amdgcn_readlane(__float_as_int(v), l));
}

#define DTF  0.00396825396825396826f
#define SQDT 0.06299407883487120442f
#define TSTEP (1.0f / 2519.0f)
#define TSC      64.0f
#define TSC_INV  0.015625f
#define TSC_T    1024.0f
#define TSCT_INV 0.0009765625f
#define INV_SQRT2 0.7071067811865475f
#define PHI_C     0.3989422804014327f
#define NEG_LN2  -0.69314718055994530942f
#define LG2_W5   -7.2134752044448170368f   /* w>=5  <=>  log2 <= -5/ln2 */
#define NRM_C    0.08908708063747479f      /* sqrt(2) * SQDT */

// ---------------- Phase 1: mean_dW[b][s] — fully parallel ----------------
__global__ __launch_bounds__(256)
void vasicek_phase1_meandw(float* __restrict__ ws) {
  const int tid = threadIdx.x;
  const int lane = tid & 63;
  const int wv = tid >> 6;
  const int wid = blockIdx.x * 4 + wv;          // 0 .. 64*2520-1
  const int b = wid / NSTEPS;
  const int s = wid - b * NSTEPS;

  uint32_t kA, kB;
  tf2x32(0u, 1u, 0u, (uint32_t)s, kA, kB);      // split(key(1))[s]
  const uint32_t k2 = kA ^ kB ^ 0x1BD11BDAu;
  const uint32_t x1base = (uint32_t)(b * NQ + lane) + kB;  // pre-keyed x1

  const float MINVAL = -0.999999940395355224609375f;
  float sum = 0.f;
#pragma unroll
  for (int i = 0; i < 4; ++i) {
    uint32_t x0 = kA, x1 = x1base + (uint32_t)(i * 64);
    R4(13,15,26,6)  x0 += kB; x1 += k2 + 1u;
    R4(17,29,16,24) x0 += k2; x1 += kA + 2u;
    R4(13,15,26,6)  x0 += kA; x1 += kB + 3u;
    R4(17,29,16,24) x0 += kB; x1 += k2 + 4u;
    R4(13,15,26,6)  x0 += k2; x1 += kA + 5u;
    const uint32_t bits = x0 ^ x1;

    // bits -> normal (fused erfinv; log2-domain branch test)
    uint32_t fb = (bits >> 9) | 0x3F800000u;
    float u = __builtin_fmaf(__uint_as_float(fb) - 1.0f, 2.0f, MINVAL);
    u = fmaxf(u, MINVAL);
    float omsq = __builtin_fmaf(u, -u, 1.0f);          // (1-u)(1+u), 1 rounding
    float lg = __builtin_amdgcn_logf(omsq);            // log2(1-u^2)
    float wc = __builtin_fmaf(lg, NEG_LN2, -2.5f);     // w - 2.5
    float p = 2.81022636e-08f;
    p = __builtin_fmaf(p, wc, 3.43273939e-07f);
    p = __builtin_fmaf(p, wc, -3.5233877e-06f);
    p = __builtin_fmaf(p, wc, -4.39150654e-06f);
    p = __builtin_fmaf(p, wc, 0.00021858087f);
    p = __builtin_fmaf(p, wc, -0.00125372503f);
    p = __builtin_fmaf(p, wc, -0.00417768164f);
    p = __builtin_fmaf(p, wc, 0.246640727f);
    p = __builtin_fmaf(p, wc, 1.50140941f);
    if (__ballot(lg <= LG2_W5)) {                      // rare (~0.3% lanes)
      float w = lg * NEG_LN2;
      float wsr = sqrtf(w) - 3.0f;
      float pr = -0.000200214257f;
      pr = __builtin_fmaf(pr, wsr, 0.000100950558f);
      pr = __builtin_fmaf(pr, wsr, 0.00134934322f);
      pr = __builtin_fmaf(pr, wsr, -0.00367342844f);
      pr = __builtin_fmaf(pr, wsr, 0.00573950773f);
      pr = __builtin_fmaf(pr, wsr, -0.0076224613f);
      pr = __builtin_fmaf(pr, wsr, 0.00943887047f);
      pr = __builtin_fmaf(pr, wsr, 1.00167406f);
      pr = __builtin_fmaf(pr, wsr, 2.83297682f);
      p = (lg <= LG2_W5) ? pr : p;
    }
    sum = __builtin_fmaf(p * u, NRM_C, sum);           // sqrt2*erfinv*sqrt_dt
  }
  sum += __shfl_xor(sum, 32, 64); sum += __shfl_xor(sum, 16, 64);
  sum += __shfl_xor(sum, 8, 64);  sum += __shfl_xor(sum, 4, 64);
  sum += __shfl_xor(sum, 2, 64);  sum += __shfl_xor(sum, 1, 64);
  if (lane == 0) ws[b * NSTEPS + s] = sum * (1.0f / 256.0f);
}

// ---- B-fragment machinery, k-PERMUTED (unchanged from R20/R23):
// B dword d of K-chunk T (lane q,n) holds W2 rows (16T+4q+d, 64+16T+4q+d)
// at column 16*(4*half+C) + n, f16x2 packed.
#define BDECL(T, C) u32x4 b_##T##_##C;
#define BINIT(T, C) { \
  const int col_ = 16 * (4 * half + (C)) + n; \
  const int r0_ = 16 * (T) + 4 * q; \
  b_##T##_##C = (u32x4){ \
    pack_f16x2(W2src[(r0_ + 0) * 128 + col_], W2src[(r0_ + 64) * 128 + col_]), \
    pack_f16x2(W2src[(r0_ + 1) * 128 + col_], W2src[(r0_ + 65) * 128 + col_]), \
    pack_f16x2(W2src[(r0_ + 2) * 128 + col_], W2src[(r0_ + 66) * 128 + col_]), \
    pack_f16x2(W2src[(r0_ + 3) * 128 + col_], W2src[(r0_ + 67) * 128 + col_])}; \
  asm volatile("" : "+a"(b_##T##_##C)); /* pin in AGPR quad */ \
}
#define MFMA1(ACC, AF, BF) \
  asm("v_mfma_f32_16x16x32_f16 %0, %1, %2, %0" : "+v"(ACC) : "v"(AF), "a"(BF));

// one-eval layer-1 for a batch: anchor A_, mid-time TV; writes regions
// 0=val, 1=d/dr*64, 2=d/dt_j*1024 (region 3 pre-zeroed).
#define STAGE3M(TV, SLOT, A_) { \
  float pre_ = __builtin_fmaf((TV), w11, __builtin_fmaf((A_), w10, c1)); \
  float e_ = eigen_erf_fast(pre_ * INV_SQRT2); \
  float cg_ = (e_ + 1.0f) * 0.5f; \
  float v_ = pre_ * cg_; \
  float ph_ = PHI_C * __expf(-0.5f * pre_ * pre_); \
  float gp_ = __builtin_fmaf(pre_, ph_, cg_); \
  ((uint16_t*)&h1x[SLOT][mlp][0][0])[2 * lane + half] = f32_to_f16bits(v_); \
  ((uint16_t*)&h1x[SLOT][mlp][1][0])[2 * lane + half] = f32_to_f16bits(gp_ * w10S); \
  ((uint16_t*)&h1x[SLOT][mlp][2][0])[2 * lane + half] = f32_to_f16bits(gp_ * w11T); \
}

// ---------------- Phase 2: scan, 64 blocks x 256 ---------------------------
__global__
__attribute__((amdgpu_flat_work_group_size(256, 256)))
__attribute__((amdgpu_waves_per_eu(1, 1)))
void vasicek_phase2_scan(
    const float* __restrict__ X, const float* __restrict__ r_ult,
    const float* __restrict__ mats,
    const float* __restrict__ Wp, const float* __restrict__ bp,
    const float* __restrict__ ln_g, const float* __restrict__ ln_b,
    const float* __restrict__ muW1, const float* __restrict__ mub1,
    const float* __restrict__ muW2, const float* __restrict__ mub2,
    const float* __restrict__ muW3, const float* __restrict__ mub3,
    const float* __restrict__ siW1, const float* __restrict__ sib1,
    const float* __restrict__ siW2, const float* __restrict__ sib2,
    const float* __restrict__ siW3, const float* __restrict__ sib3,
    const float* __restrict__ ws, float* __restrict__ out) {
  // [slot][mlp][region: 0=val,1=dr,2=dt,3=zero][68 dw] (stride 272B==16 mod 128)
  __shared__ __align__(16) uint32_t h1x[2][2][4][68];
  __shared__ __align__(16) float meanw[MWPAD];
  __shared__ float part[256];
  __shared__ float mbuf[64];
  __shared__ float ctx_lds[192];
  __shared__ __align__(16) float msum[2][4][4];   // [slot][wave][PV,PR,PT,pad]

  const int t = threadIdx.x;
  const int b = blockIdx.x;
  const int lane = t & 63;
  const int wv = t >> 6;

  for (int i = t; i < MWPAD; i += 256)
    meanw[i] = i < NSTEPS ? ws[b * NSTEPS + i] : 0.f;

  // ---- context aggregator (all 256 threads, one T-row each) ----
  float h[64];
  {
    float x0 = X[(b * NT + t) * 2 + 0];
    float x1 = X[(b * NT + t) * 2 + 1];
    float s = 0.f;
#pragma unroll
    for (int c = 0; c < 64; ++c) {
      float pre = __builtin_fmaf(x1, Wp[64 + c], x0 * Wp[c]) + bp[c];
      h[c] = eigen_tanh(pre);
      s += h[c];
    }
    float m = s * 0.015625f;
    float vs = 0.f;
#pragma unroll
    for (int c = 0; c < 64; ++c) { float d = h[c] - m; vs = __builtin_fmaf(d, d, vs); }
    float den = sqrtf(vs * 0.015625f + 1e-5f);
#pragma unroll
    for (int c = 0; c < 64; ++c)
      h[c] = ((h[c] - m) / den) * ln_g[c] + ln_b[c];
  }
#pragma unroll
  for (int c = 0; c < 64; ++c) {
    float v = h[c];
    v += __shfl_xor(v, 32, 64); v += __shfl_xor(v, 16, 64);
    v += __shfl_xor(v, 8, 64);  v += __shfl_xor(v, 4, 64);
    v += __shfl_xor(v, 2, 64);  v += __shfl_xor(v, 1, 64);
    if (lane == 0) part[wv * 64 + c] = v;
  }
  __syncthreads();
  if (t < 64) {
    float m = ((part[t] + part[64 + t]) + (part[128 + t] + part[192 + t])) * (1.0f / 256.0f);
    mbuf[t] = m;
    ctx_lds[t] = m;
  }
  __syncthreads();
#pragma unroll
  for (int c = 0; c < 64; ++c) {
    float d = h[c] - mbuf[c];
    float v = d * d;
    v += __shfl_xor(v, 32, 64); v += __shfl_xor(v, 16, 64);
    v += __shfl_xor(v, 8, 64);  v += __shfl_xor(v, 4, 64);
    v += __shfl_xor(v, 2, 64);  v += __shfl_xor(v, 1, 64);
    if (lane == 0) part[wv * 64 + c] = v;
  }
  if (t == 255) {
#pragma unroll
    for (int c = 0; c < 64; ++c) ctx_lds[128 + c] = h[c];
  }
  __syncthreads();
  if (t < 64) {
    float vs = (part[t] + part[64 + t]) + (part[128 + t] + part[192 + t]);
    ctx_lds[64 + t] = sqrtf(vs / 255.0f);
  }
  __syncthreads();

  // ---- per-wave roles: mlp = wv>>1 (0=mu,1=si), half = wv&1 ----
  const int mlp = wv >> 1;
  const int half = wv & 1;
  const int jH = 64 * half + lane;            // layer-1 element ownership
  const float* W1 = mlp == 0 ? muW1 : siW1;
  const float* W2src = mlp == 0 ? muW2 : siW2;
  float c1 = (mlp == 0 ? mub1 : sib1)[jH];
  for (int c = 0; c < 192; ++c) {
    const float cx = ctx_lds[c];
    c1 = __builtin_fmaf(cx, W1[(2 + c) * 128 + jH], c1);
  }
  const float w10 = W1[jH], w11 = W1[128 + jH];
  const float w10S = w10 * TSC;
  const float w11T = w11 * (TSTEP * TSC_T);
  const float b3mu = mub3[0], b3si = sib3[0];

  const int q = lane >> 4, n = lane & 15;

  // per-lane epilogue constants: this lane's single column (chunk C = q)
  const float* b2p = mlp == 0 ? mub2 : sib2;
  const float* w3p = mlp == 0 ? muW3 : siW3;
  const int colE = 64 * half + 16 * q + n;
  const float b2E = b2p[colE], w3E = w3p[colE];

  // this wave's 4 col-tiles of its W2 -> 16 AGPR quads (one-time; pinned)
  BDECL(0,0) BDECL(0,1) BDECL(0,2) BDECL(0,3)
  BDECL(1,0) BDECL(1,1) BDECL(1,2) BDECL(1,3)
  BDECL(2,0) BDECL(2,1) BDECL(2,2) BDECL(2,3)
  BDECL(3,0) BDECL(3,1) BDECL(3,2) BDECL(3,3)
  BINIT(0,0) BINIT(0,1) BINIT(0,2) BINIT(0,3)
  BINIT(1,0) BINIT(1,1) BINIT(1,2) BINIT(1,3)
  BINIT(2,0) BINIT(2,1) BINIT(2,2) BINIT(2,3)
  BINIT(3,0) BINIT(3,1) BINIT(3,2) BINIT(3,3)

  // zero region 3 (A-rows 3,7,11,15) for both slots of this wave's MLP
  h1x[0][mlp][3][lane] = 0u; h1x[1][mlp][3][lane] = 0u;
  if (lane < 4) { h1x[0][mlp][3][64 + lane] = 0u; h1x[1][mlp][3][64 + lane] = 0u; }

  // A-frag base pointers: region (n&3) of this wave's MLP, quad offset q.
  const u32x4* hq0 = ((const u32x4*)&h1x[0][mlp][0][0]) + 17 * (n & 3) + q;
  const u32x4* hq1 = ((const u32x4*)&h1x[1][mlp][0][0]) + 17 * (n & 3) + q;

  // ---- scan state (uniform) + per-lane area ----
  const float r0 = r_ult[b];
  float r_s = r0;
  float aNow = r0, aUpd = r0, aMid = r0;   // anchors: batch k, k+1, k+2
  float area_p = 0.f;
  const int sj = lane;                     // step-in-batch (64-wide)
  const float jj = (float)sj - 31.5f;

  // ---- prologue: layer-1 one-eval for batch 0 -> slot 0, anchor r0 ----
  STAGE3M(TSTEP * 31.5f, 0, r0)
  __syncthreads();

  // ---- main loop: body k: scan batch k, MFMA batch k+1, STAGE3 batch k+2
#pragma unroll 1
  for (int k = -1; k < NBODY; ++k) {
    const int sl = k & 1;        // msum slot (batch k); h1 write slot (batch k+2)
    const int so = sl ^ 1;       // h1 read slot (batch k+1); msum write slot

    // --- LDS reads issued early ---
    f32x4 m0 = *(const f32x4*)&msum[sl][0][0];
    f32x4 m1 = *(const f32x4*)&msum[sl][1][0];
    f32x4 m2 = *(const f32x4*)&msum[sl][2][0];
    f32x4 m3 = *(const f32x4*)&msum[sl][3][0];
    const int u0 = k < 0 ? 0 : 64 * k;
    const float mwj = meanw[u0 + sj];
    const u32x4* hq = so ? hq1 : hq0;
    u32x4 af0 = hq[0], af1 = hq[4], af2 = hq[8], af3 = hq[12];

    // --- MFMA batch k+1 (matrix pipe) ---
    f32x4 ac0 = {0,0,0,0}, ac1 = {0,0,0,0}, ac2 = {0,0,0,0}, ac3 = {0,0,0,0};
    MFMA1(ac0, af0, b_0_0) MFMA1(ac1, af0, b_0_1) MFMA1(ac2, af0, b_0_2) MFMA1(ac3, af0, b_0_3)
    MFMA1(ac0, af1, b_1_0) MFMA1(ac1, af1, b_1_1) MFMA1(ac2, af1, b_1_2) MFMA1(ac3, af1, b_1_3)
    MFMA1(ac0, af2, b_2_0) MFMA1(ac1, af2, b_2_1) MFMA1(ac2, af2, b_2_2) MFMA1(ac3, af2, b_2_3)
    MFMA1(ac0, af3, b_3_0) MFMA1(ac1, af3, b_3_1) MFMA1(ac2, af3, b_3_2) MFMA1(ac3, af3, b_3_3)

    // --- STAGE3 batch k+2 (anchor aMid from previous rotation) ---
    STAGE3M(TSTEP * ((float)(64 * (k + 2)) + 31.5f), sl, aMid)

    // --- affine scan for batch k (lane sj = step 64k+sj) ---
    {
      float MV = (m0[0] + m1[0]) + b3mu;
      float MR = (m0[1] + m1[1]) * TSC_INV;
      float MT = (m0[2] + m1[2]) * TSCT_INV;
      float ZV = (m2[0] + m3[0]) + b3si;
      float ZR = (m2[1] + m3[1]) * TSC_INV;
      float ZT = (m2[2] + m3[2]) * TSCT_INV;
      // softplus at z_mid + 2nd-order in the (r-independent) time offset
      float e_ = __expf(-fabsf(ZV));
      float sp = fmaxf(ZV, 0.f) + __logf(1.0f + e_) + 1e-5f;
      float inv = fast_rcp(1.0f + e_);
      float sgm = ZV > 0.f ? inv : 1.0f - inv;
      float hcv = 0.5f * sgm * (1.0f - sgm);
      float dzt = jj * ZT;
      float sigj = __builtin_fmaf(2.0f * hcv, dzt, sgm);    // sigma(z_mid+dzt)
      float spj  = __builtin_fmaf(__builtin_fmaf(hcv, dzt, sgm), dzt, sp);
      float sZR = sigj * ZR;
      // beta, alpha
      float beta = __builtin_fmaf(sZR, mwj, __builtin_fmaf(MR, DTF, 1.0f));
      float am_ = __builtin_fmaf(jj, MT, __builtin_fmaf(-aNow, MR, MV));
      float as_ = __builtin_fmaf(-aNow, sZR, spj);
      float alpha = __builtin_fmaf(am_, DTF, as_ * mwj);
      // inclusive affine prefix scan over 64 lanes:
      // 4 in-row rounds, then row_bcast15 (rows1,3), row_bcast31 (rows2,3)
      float B = beta, A = alpha;
      {
        float Bs = dpp_mov<0x111, 0xf>(B, 1.0f), As = dpp_mov<0x111, 0xf>(A, 0.0f);
        A = __builtin_fmaf(B, As, A); B = B * Bs;
        Bs = dpp_mov<0x112, 0xf>(B, 1.0f); As = dpp_mov<0x112, 0xf>(A, 0.0f);
        A = __builtin_fmaf(B, As, A); B = B * Bs;
        Bs = dpp_mov<0x114, 0xf>(B, 1.0f); As = dpp_mov<0x114, 0xf>(A, 0.0f);
        A = __builtin_fmaf(B, As, A); B = B * Bs;
        Bs = dpp_mov<0x118, 0xf>(B, 1.0f); As = dpp_mov<0x118, 0xf>(A, 0.0f);
        A = __builtin_fmaf(B, As, A); B = B * Bs;
        Bs = dpp_mov<0x142, 0xa>(B, 1.0f); As = dpp_mov<0x142, 0xa>(A, 0.0f);
        A = __builtin_fmaf(B, As, A); B = B * Bs;
        Bs = dpp_mov<0x143, 0xc>(B, 1.0f); As = dpp_mov<0x143, 0xc>(A, 0.0f);
        A = __builtin_fmaf(B, As, A); B = B * Bs;
      }
      float rho = __builtin_fmaf(B, r_s, A);
      if (k >= 0) {
        float contrib = (64 * k + sj) < NSTEPS ? rho * DTF : 0.f;
        area_p += contrib;
        float rn = readlane_f(rho, 63);
        // drift-only prediction for batch k+3 (mid-step distance ~160.5)
        float aNew = __builtin_fmaf(MV, 160.5f * DTF, rn);
        r_s = rn;
        aNow = aUpd; aUpd = aMid; aMid = aNew;
      }
    }

    // --- MFMA dst -> VALU read hazard fence ---
    asm volatile("s_nop 7\n\ts_nop 7"
                 : "+v"(ac0), "+v"(ac1), "+v"(ac2), "+v"(ac3));

    // --- epilogue batch k+1: lane (q,n) handles its single column (C=q) ---
    {
      const f32x4 aq = q == 0 ? ac0 : q == 1 ? ac1 : q == 2 ? ac2 : ac3;
      float yv = aq[0] + b2E;
      float ytr = aq[1];                 // d/dr row (scaled TSC)
      float ytt = aq[2];                 // d/dt row (scaled TSC_T)
      float ev = eigen_erf_fast(yv * INV_SQRT2);
      float cv = (ev + 1.0f) * 0.5f;
      float pv = yv * cv * w3E;
      float phv = PHI_C * __expf(-0.5f * yv * yv);
      float g2p = __builtin_fmaf(yv, phv, cv) * w3E;
      float pr = g2p * ytr;
      float pt = g2p * ytt;
      pv = dpp_reduce63(pv);
      pr = dpp_reduce63(pr);
      pt = dpp_reduce63(pt);
      if (lane == 63) {
        *(f32x4*)&msum[so][wv][0] = (f32x4){pv, pr, pt, 0.f};
      }
    }
    __syncthreads();  // publish msum[so] (batch k+1) + h1x[sl] (batch k+2)
  }

  // area: all 64 lanes hold distinct per-step partials
  float area = area_p;
  area += __shfl_xor(area, 1, 64);
  area += __shfl_xor(area, 2, 64);
  area += __shfl_xor(area, 4, 64);
  area += __shfl_xor(area, 8, 64);
  area += __shfl_xor(area, 16, 64);
  area += __shfl_xor(area, 32, 64);

  if (t < NMAT) {
    float mx = mats[0];
#pragma unroll
    for (int i = 1; i < NMAT; ++i) mx = fmaxf(mx, mats[i]);
    const float mm = mats[t];
    const float frac = mm / (mx + 1e-12f);
    out[b * NMAT + t] = (area * frac) / (mm + 1e-12f);
  }
}

extern "C" void kernel_launch(void* const* d_in, const int* in_sizes, int n_in,
                              void* d_out, int out_size, void* d_ws, size_t ws_size,
                              hipStream_t stream) {
  (void)in_sizes; (void)n_in; (void)ws_size; (void)out_size;
  const float* X      = (const float*)d_in[0];
  const float* r_ult  = (const float*)d_in[1];
  const float* mats   = (const float*)d_in[2];
  const float* Wp     = (const float*)d_in[3];
  const float* bp     = (const float*)d_in[4];
  const float* ln_g   = (const float*)d_in[5];
  const float* ln_b   = (const float*)d_in[6];
  const float* muW1   = (const float*)d_in[7];
  const float* mub1   = (const float*)d_in[8];
  const float* muW2   = (const float*)d_in[9];
  const float* mub2   = (const float*)d_in[10];
  const float* muW3   = (const float*)d_in[11];
  const float* mub3   = (const float*)d_in[12];
  const float* siW1   = (const float*)d_in[13];
  const float* sib1   = (const float*)d_in[14];
  const float* siW2   = (const float*)d_in[15];
  const float* sib2   = (const float*)d_in[16];
  const float* siW3   = (const float*)d_in[17];
  const float* sib3   = (const float*)d_in[18];
  float* ws = (float*)d_ws;   // 64*2520*4 = 645,120 bytes

  hipLaunchKernelGGL(vasicek_phase1_meandw,
                     dim3(NB * NSTEPS / 4), dim3(256), 0, stream, ws);
  hipLaunchKernelGGL(vasicek_phase2_scan,
                     dim3(NB), dim3(256), 0, stream,
                     X, r_ult, mats, Wp, bp, ln_g, ln_b,
                     muW1, mub1, muW2, mub2, muW3, mub3,
                     siW1, sib1, siW2, sib2, siW3, sib3,
                     ws, (float*)d_out);
}